// Round 2
// baseline (297.659 us; speedup 1.0000x reference)
//
#include <hip/hip_runtime.h>

#define NA 1000
#define HALF 500
#define ND 513
#define IMG 512
#define CROP 362
#define TOP ((IMG - CROP) / 2)          // 75
#define NPIX (CROP * CROP)              // 131044
#define TILE 16
#define NTILE ((CROP + TILE - 1) / TILE) // 23

// Static device buffers (rewritten every call; deterministic).
// g_yT: [group(2)][angle(1000)][det(513)][4 floats] - 4 batch values contiguous.
// g_part: [group(2)][half(2)][pix(NPIX)][4 floats] partial sums per angle-half.
__device__ float2 g_tab[NA];
__device__ float  g_yT[(size_t)2 * NA * ND * 4];
__device__ float  g_part[(size_t)2 * 2 * NPIX * 4];

__global__ void table_kernel() {
    int a = blockIdx.x * blockDim.x + threadIdx.x;
    if (a >= NA) return;
    double th = (double)a * (3.14159265358979323846 / (double)NA);
    float delta_f = (float)(2.0 * 0.13 / (double)(ND - 1));
    double inv = 1.0 / (double)delta_f;
    g_tab[a] = make_float2((float)(cos(th) * inv), (float)(sin(th) * inv));
}

// x[b][a][d] (b-major) -> g_yT[g][a][d][4]
__global__ void transpose_kernel(const float* __restrict__ x) {
    int t = blockIdx.x * blockDim.x + threadIdx.x;   // t = a*ND + d
    if (t >= NA * ND) return;
    const int S = NA * ND;
    float4 lo = make_float4(x[0 * S + t], x[1 * S + t], x[2 * S + t], x[3 * S + t]);
    float4 hi = make_float4(x[4 * S + t], x[5 * S + t], x[6 * S + t], x[7 * S + t]);
    ((float4*)g_yT)[t]     = lo;
    ((float4*)g_yT)[S + t] = hi;
}

// block = 16x16 pixel tile; blockIdx.z = group(2) x angle-half(2).
// Each thread accumulates 500 angles for 4 batches (one group) of one pixel.
__launch_bounds__(256)
__global__ void bp_kernel() {
    __shared__ float2 s_tab[HALF];
    int g = blockIdx.z >> 1;
    int h = blockIdx.z & 1;
    int a0 = h * HALF;
    int tid = threadIdx.y * TILE + threadIdx.x;
    for (int t = tid; t < HALF; t += 256) s_tab[t] = g_tab[a0 + t];
    __syncthreads();

    int i = blockIdx.y * TILE + threadIdx.y;   // output row -> X
    int j = blockIdx.x * TILE + threadIdx.x;   // output col -> Y
    int ic = min(i, CROP - 1);
    int jc = min(j, CROP - 1);

    const float step = (float)(0.26 / 511.0);
    float X = fmaf((float)(TOP + ic), step, -0.13f);
    float Y = fmaf((float)(TOP + jc), step, -0.13f);

    const float4* __restrict__ row =
        ((const float4*)g_yT) + (size_t)g * (NA * ND) + (size_t)a0 * ND;

    float4 acc = make_float4(0.f, 0.f, 0.f, 0.f);
    // p in [0.23, 511.77] for all crop pixels -> i0 in [0,511]: no clamps needed.
    #pragma unroll 4
    for (int a = 0; a < HALF; ++a) {
        float2 cs = s_tab[a];
        float p  = fmaf(X, cs.x, fmaf(Y, cs.y, 256.0f));
        float fi = floorf(p);
        float w  = p - fi;
        int   i0 = (int)fi;
        float4 v0 = row[i0];
        float4 v1 = row[i0 + 1];
        row += ND;
        float w0 = 1.0f - w;
        acc.x = fmaf(v0.x, w0, fmaf(v1.x, w, acc.x));
        acc.y = fmaf(v0.y, w0, fmaf(v1.y, w, acc.y));
        acc.z = fmaf(v0.z, w0, fmaf(v1.z, w, acc.z));
        acc.w = fmaf(v0.w, w0, fmaf(v1.w, w, acc.w));
    }

    if (i < CROP && j < CROP) {
        ((float4*)g_part)[(size_t)(g * 2 + h) * NPIX + (size_t)i * CROP + j] = acc;
    }
}

// out[b][pix] = (part[g][0][pix][c] + part[g][1][pix][c]) * pi/NA
__global__ void combine_kernel(float* __restrict__ out) {
    int t = blockIdx.x * 256 + threadIdx.x;      // t = g*NPIX + pix
    if (t >= 2 * NPIX) return;
    int g = (t >= NPIX) ? 1 : 0;
    int pix = t - g * NPIX;
    float4 u = ((const float4*)g_part)[(size_t)(g * 2 + 0) * NPIX + pix];
    float4 v = ((const float4*)g_part)[(size_t)(g * 2 + 1) * NPIX + pix];
    const float scale = (float)(3.14159265358979323846 / 1000.0);
    int ob = g * 4;
    out[(size_t)(ob + 0) * NPIX + pix] = (u.x + v.x) * scale;
    out[(size_t)(ob + 1) * NPIX + pix] = (u.y + v.y) * scale;
    out[(size_t)(ob + 2) * NPIX + pix] = (u.z + v.z) * scale;
    out[(size_t)(ob + 3) * NPIX + pix] = (u.w + v.w) * scale;
}

extern "C" void kernel_launch(void* const* d_in, const int* in_sizes, int n_in,
                              void* d_out, int out_size, void* d_ws, size_t ws_size,
                              hipStream_t stream) {
    const float* x = (const float*)d_in[0];
    float* out = (float*)d_out;

    table_kernel<<<(NA + 255) / 256, 256, 0, stream>>>();
    transpose_kernel<<<(NA * ND + 255) / 256, 256, 0, stream>>>(x);

    dim3 bgrid(NTILE, NTILE, 4);
    dim3 bblock(TILE, TILE);
    bp_kernel<<<bgrid, bblock, 0, stream>>>();

    combine_kernel<<<(2 * NPIX + 255) / 256, 256, 0, stream>>>(out);
}

// Round 3
// 158.485 us; speedup vs baseline: 1.8781x; 1.8781x over previous
//
#include <hip/hip_runtime.h>
#include <hip/hip_bf16.h>

#define NA 1000
#define NCH 4
#define CHUNK 250              // NA / NCH
#define ND 513
#define IMG 512
#define CROP 362
#define TOP ((IMG - CROP) / 2) // 75
#define NPIX (CROP * CROP)     // 131044
#define PIXBLK 512             // ceil(NPIX/256)

// 16-byte vector load that is only guaranteed 8-byte aligned (cells are 8 B).
typedef uint4 __attribute__((aligned(8))) uint4a8;

// Static device buffers, fully rewritten every call (deterministic).
// g_lo/g_hi: [angle][det][4 bf16] -> batches 0-3 / 4-7. Cell = 8 B (uint2).
// g_part:    [chunk][batch][pix] f32 partial sums.
__device__ float2 g_tab[NA];
__device__ unsigned int g_lo[(size_t)NA * ND * 2];
__device__ unsigned int g_hi[(size_t)NA * ND * 2];
__device__ float g_part[(size_t)NCH * 8 * NPIX];

__global__ void table_kernel() {
    int a = blockIdx.x * blockDim.x + threadIdx.x;
    if (a >= NA) return;
    double th = (double)a * (3.14159265358979323846 / (double)NA);
    float delta_f = (float)(2.0 * 0.13 / (double)(ND - 1));
    double inv = 1.0 / (double)delta_f;
    g_tab[a] = make_float2((float)(cos(th) * inv), (float)(sin(th) * inv));
}

__device__ __forceinline__ unsigned short to_bf16(float v) {
    __hip_bfloat16 b = __float2bfloat16(v);   // RNE
    return *(unsigned short*)&b;
}

// x[b][a][d] (b-major, f32) -> packed bf16 cells.
__global__ void pack_kernel(const float* __restrict__ x) {
    int t = blockIdx.x * blockDim.x + threadIdx.x;   // t = a*ND + d
    if (t >= NA * ND) return;
    const int S = NA * ND;
    unsigned int lo0 = (unsigned int)to_bf16(x[0 * S + t]) |
                       ((unsigned int)to_bf16(x[1 * S + t]) << 16);
    unsigned int lo1 = (unsigned int)to_bf16(x[2 * S + t]) |
                       ((unsigned int)to_bf16(x[3 * S + t]) << 16);
    unsigned int hi0 = (unsigned int)to_bf16(x[4 * S + t]) |
                       ((unsigned int)to_bf16(x[5 * S + t]) << 16);
    unsigned int hi1 = (unsigned int)to_bf16(x[6 * S + t]) |
                       ((unsigned int)to_bf16(x[7 * S + t]) << 16);
    ((uint2*)g_lo)[t] = make_uint2(lo0, lo1);
    ((uint2*)g_hi)[t] = make_uint2(hi0, hi1);
}

__device__ __forceinline__ float bf_lo(unsigned int u) {
    return __uint_as_float(u << 16);
}
__device__ __forceinline__ float bf_hi(unsigned int u) {
    return __uint_as_float(u & 0xFFFF0000u);
}

// One thread = one pixel, all 8 batches, 250 angles (blockIdx.y = chunk).
__launch_bounds__(256)
__global__ void bp_kernel() {
    __shared__ float2 s_tab[CHUNK];
    int ch = blockIdx.y;
    int a0 = ch * CHUNK;
    for (int t = threadIdx.x; t < CHUNK; t += 256) s_tab[t] = g_tab[a0 + t];
    __syncthreads();

    int pix = blockIdx.x * 256 + threadIdx.x;
    int pc = min(pix, NPIX - 1);
    int i = pc / CROP;                 // -> X (output row)
    int j = pc - i * CROP;             // -> Y (output col, lane-contiguous)

    const float step = (float)(0.26 / 511.0);
    float X = fmaf((float)(TOP + i), step, -0.13f);
    float Y = fmaf((float)(TOP + j), step, -0.13f);

    const uint2* __restrict__ lo = ((const uint2*)g_lo) + (size_t)a0 * ND;
    const uint2* __restrict__ hi = ((const uint2*)g_hi) + (size_t)a0 * ND;

    float acc0 = 0.f, acc1 = 0.f, acc2 = 0.f, acc3 = 0.f;
    float acc4 = 0.f, acc5 = 0.f, acc6 = 0.f, acc7 = 0.f;

    // p in [0.23, 511.77] for all crop pixels -> i0 in [0,511], i1 <= 512:
    // always in-bounds, no clamps needed.
    for (int a = 0; a < CHUNK; ++a) {
        float2 cs = s_tab[a];
        float p  = fmaf(X, cs.x, fmaf(Y, cs.y, 256.0f));
        float fi = floorf(p);
        float w  = p - fi;
        float w0 = 1.0f - w;
        int idx  = a * ND + (int)fi;
        // A: cells i0,i0+1 batches 0-3; B: same for batches 4-7.
        uint4 A = *(const uint4a8*)(lo + idx);
        uint4 B = *(const uint4a8*)(hi + idx);
        acc0 = fmaf(bf_lo(A.x), w0, fmaf(bf_lo(A.z), w, acc0));
        acc1 = fmaf(bf_hi(A.x), w0, fmaf(bf_hi(A.z), w, acc1));
        acc2 = fmaf(bf_lo(A.y), w0, fmaf(bf_lo(A.w), w, acc2));
        acc3 = fmaf(bf_hi(A.y), w0, fmaf(bf_hi(A.w), w, acc3));
        acc4 = fmaf(bf_lo(B.x), w0, fmaf(bf_lo(B.z), w, acc4));
        acc5 = fmaf(bf_hi(B.x), w0, fmaf(bf_hi(B.z), w, acc5));
        acc6 = fmaf(bf_lo(B.y), w0, fmaf(bf_lo(B.w), w, acc6));
        acc7 = fmaf(bf_hi(B.y), w0, fmaf(bf_hi(B.w), w, acc7));
    }

    if (pix < NPIX) {
        float* p0 = g_part + (size_t)ch * 8 * NPIX + pix;
        p0[0 * NPIX] = acc0; p0[1 * NPIX] = acc1;
        p0[2 * NPIX] = acc2; p0[3 * NPIX] = acc3;
        p0[4 * NPIX] = acc4; p0[5 * NPIX] = acc5;
        p0[6 * NPIX] = acc6; p0[7 * NPIX] = acc7;
    }
}

// out[b][pix] = sum_ch part[ch][b][pix] * pi/NA
__global__ void combine_kernel(float* __restrict__ out) {
    int t = blockIdx.x * 256 + threadIdx.x;      // t over 8*NPIX, batch-major
    if (t >= 8 * NPIX) return;
    const float scale = (float)(3.14159265358979323846 / 1000.0);
    float s = 0.f;
    #pragma unroll
    for (int ch = 0; ch < NCH; ++ch) s += g_part[(size_t)ch * 8 * NPIX + t];
    out[t] = s * scale;
}

extern "C" void kernel_launch(void* const* d_in, const int* in_sizes, int n_in,
                              void* d_out, int out_size, void* d_ws, size_t ws_size,
                              hipStream_t stream) {
    const float* x = (const float*)d_in[0];
    float* out = (float*)d_out;

    table_kernel<<<(NA + 255) / 256, 256, 0, stream>>>();
    pack_kernel<<<(NA * ND + 255) / 256, 256, 0, stream>>>(x);

    dim3 bgrid(PIXBLK, NCH);
    bp_kernel<<<bgrid, 256, 0, stream>>>();

    combine_kernel<<<(8 * NPIX + 255) / 256, 256, 0, stream>>>(out);
}